// Round 6
// baseline (434.791 us; speedup 1.0000x reference)
//
#include <hip/hip_runtime.h>

// GCN on MI355X (gfx950). n=100000, 1.6M edges, D 128/128/64.
// Round 6: SpMM inner loop unrolled 4 edges deep with 4 independent
// accumulator sets -> 4 outstanding gathers per lane (was 2). Profile
// showed spmm latency-bound: BW 3.5/6.3 TB/s, VALUBusy 30%, occupancy 68%.
// Everything else unchanged from round 5.

typedef unsigned int u32;
typedef unsigned short u16;
typedef __attribute__((ext_vector_type(8))) short bf16x8;
typedef __attribute__((ext_vector_type(4))) float f32x4;

constexpr int NN = 100000;
constexpr int NE = 1600000;
constexpr int PAD = 100352;            // 196 * 512
constexpr int NBUCK = 196;             // buckets of 512 rows
constexpr int BCAP = 10240;            // per-bucket capacity (mean 8163)
constexpr int EPB = 2048;              // edges per part1 block

__device__ __forceinline__ u16 f2bf(float f) {   // RNE round to bf16
    u32 x = __float_as_uint(f);
    x += 0x7fffu + ((x >> 16) & 1u);
    return (u16)(x >> 16);
}

// ---------------------------------------------------------------------------
// GEMM: C_bf16[n x DO] = H @ W^T, mfma_f32_16x16x32_bf16, fp32 accum.
// ---------------------------------------------------------------------------
template<int DO, bool FP32IN>
__global__ __launch_bounds__(256)
void gemm_mfma(const void* __restrict__ Hin, const u16* __restrict__ Wb,
               u16* __restrict__ Cb, int n)
{
    constexpr int PADW = DO + 8;
    __shared__ u16 sC[4 * 16 * PADW];
    const int tid  = threadIdx.x;
    const int w    = tid >> 6;
    const int lane = tid & 63;
    const int m    = lane & 15;
    const int q    = lane >> 4;
    const int row  = blockIdx.x * 64 + w * 16 + m;

    bf16x8 afrag[4];
    #pragma unroll
    for (int kc = 0; kc < 4; ++kc) {
        bf16x8 a = {0, 0, 0, 0, 0, 0, 0, 0};
        if (row < n) {
            if (FP32IN) {
                const float* H = (const float*)Hin;
                const float4* p = (const float4*)(H + (size_t)row * 128 + kc * 32 + q * 8);
                const float4 u0 = p[0];
                const float4 u1 = p[1];
                a[0] = (short)f2bf(u0.x); a[1] = (short)f2bf(u0.y);
                a[2] = (short)f2bf(u0.z); a[3] = (short)f2bf(u0.w);
                a[4] = (short)f2bf(u1.x); a[5] = (short)f2bf(u1.y);
                a[6] = (short)f2bf(u1.z); a[7] = (short)f2bf(u1.w);
            } else {
                const u16* H = (const u16*)Hin;
                a = *(const bf16x8*)(H + (size_t)row * 128 + kc * 32 + q * 8);
            }
        }
        afrag[kc] = a;
    }

    #pragma unroll 4
    for (int ct = 0; ct < DO / 16; ++ct) {
        f32x4 acc = {0.f, 0.f, 0.f, 0.f};
        #pragma unroll
        for (int kc = 0; kc < 4; ++kc) {
            const bf16x8 b = *(const bf16x8*)(Wb + (ct * 16 + m) * 128 + kc * 32 + q * 8);
            acc = __builtin_amdgcn_mfma_f32_16x16x32_bf16(afrag[kc], b, acc, 0, 0, 0);
        }
        #pragma unroll
        for (int r = 0; r < 4; ++r)
            sC[(w * 16 + q * 4 + r) * PADW + ct * 16 + m] = f2bf(acc[r]);
    }
    __syncthreads();

    const int g    = lane >> 2;
    const int cb   = (lane & 3) * (DO / 4);
    const int grow = blockIdx.x * 64 + w * 16 + g;
    if (grow < n) {
        #pragma unroll
        for (int i = 0; i < DO / 32; ++i) {
            const int4 v = *(const int4*)&sC[(w * 16 + g) * PADW + cb + i * 8];
            *(int4*)(Cb + (size_t)grow * DO + cb + i * 8) = v;
        }
    }
}

__global__ __launch_bounds__(256)
void wcvt_kernel(const float* __restrict__ W0, const float* __restrict__ W1,
                 const float* __restrict__ W2, u16* __restrict__ w0b,
                 u16* __restrict__ w1b, u16* __restrict__ w2b)
{
    const int i = blockIdx.x * 256 + threadIdx.x;
    if (i < 128 * 128) { w0b[i] = f2bf(W0[i]); w1b[i] = f2bf(W1[i]); }
    if (i < 64 * 128)  { w2b[i] = f2bf(W2[i]); }
}

// ---------------------------------------------------------------------------
// part1: bucket partition, streaming two-pass (low VGPR, no global per-row
// atomics).
// ---------------------------------------------------------------------------
__global__ __launch_bounds__(256)
void part1_kernel(const int* __restrict__ erow, const int* __restrict__ ecol,
                  const float* __restrict__ eval, int* __restrict__ bcur,
                  int2* __restrict__ part)
{
    __shared__ int shist[NBUCK];
    __shared__ int sbase[NBUCK];
    const int tid = threadIdx.x;
    for (int i = tid; i < NBUCK; i += 256) shist[i] = 0;
    __syncthreads();

    const int base = blockIdx.x * EPB;
    #pragma unroll
    for (int j = 0; j < EPB / 256; ++j) {
        const int e = base + j * 256 + tid;
        if (e < NE) atomicAdd(&shist[erow[e] >> 9], 1);
    }
    __syncthreads();
    for (int i = tid; i < NBUCK; i += 256) {
        const int c = shist[i];
        sbase[i] = c ? atomicAdd(&bcur[i], c) : 0;
        shist[i] = 0;
    }
    __syncthreads();
    #pragma unroll
    for (int j = 0; j < EPB / 256; ++j) {
        const int e = base + j * 256 + tid;
        if (e < NE) {
            const int r = erow[e];
            const int b = r >> 9;
            const int rk = atomicAdd(&shist[b], 1);
            part[b * BCAP + sbase[b] + rk] =
                make_int2(((r & 511) << 17) | ecol[e], __float_as_int(eval[e]));
        }
    }
}

// Exclusive scan of 196 bucket totals (single block).
__global__ __launch_bounds__(256)
void scanb_kernel(const int* __restrict__ bcur, int* __restrict__ bbase)
{
    __shared__ int sdata[256];
    const int tid = threadIdx.x;
    const int v = (tid < NBUCK) ? bcur[tid] : 0;
    sdata[tid] = v;
    __syncthreads();
    #pragma unroll
    for (int off = 1; off < 256; off <<= 1) {
        const int val = (tid >= off) ? sdata[tid - off] : 0;
        __syncthreads();
        sdata[tid] += val;
        __syncthreads();
    }
    if (tid < NBUCK) bbase[tid] = sdata[tid] - v;
}

// ---------------------------------------------------------------------------
// part2: per-bucket row histogram + 512-wide LDS scan -> offs; LDS-cursor
// scatter into the bucket's contiguous CSR slice.
// ---------------------------------------------------------------------------
__global__ __launch_bounds__(256)
void part2_kernel(const int* __restrict__ bcur, const int* __restrict__ bbase,
                  const int2* __restrict__ part, int* __restrict__ offs,
                  int2* __restrict__ pce)
{
    __shared__ int scnt[512];
    __shared__ int sdata[256];
    __shared__ int rowoff[512];
    const int b = blockIdx.x;
    const int tid = threadIdx.x;
    scnt[tid] = 0; scnt[tid + 256] = 0;
    __syncthreads();

    const int cnt = bcur[b];
    const int gb  = bbase[b];
    const int2* src = part + (size_t)b * BCAP;

    for (int i = tid; i < cnt; i += 256)
        atomicAdd(&scnt[((u32)src[i].x) >> 17], 1);
    __syncthreads();

    const int c0 = scnt[2 * tid];
    const int c1 = scnt[2 * tid + 1];
    const int tsum = c0 + c1;
    sdata[tid] = tsum;
    __syncthreads();
    #pragma unroll
    for (int off = 1; off < 256; off <<= 1) {
        const int val = (tid >= off) ? sdata[tid - off] : 0;
        __syncthreads();
        sdata[tid] += val;
        __syncthreads();
    }
    const int excl = sdata[tid] - tsum;
    rowoff[2 * tid]     = gb + excl;
    rowoff[2 * tid + 1] = gb + excl + c0;
    __syncthreads();

    offs[b * 512 + tid]       = rowoff[tid];
    offs[b * 512 + 256 + tid] = rowoff[tid + 256];
    __syncthreads();

    for (int i = tid; i < cnt; i += 256) {
        const int2 ev = src[i];
        const int rl = ((u32)ev.x) >> 17;
        const int pos = atomicAdd(&rowoff[rl], 1);
        pce[pos] = make_int2(ev.x & 0x1FFFF, ev.y);
    }
}

// ---------------------------------------------------------------------------
// CSR SpMM over bf16 features, fp32 accumulate. 16 lanes/row, 16 rows/block.
// 4-edge unroll, 4 accumulator sets -> 4 outstanding gathers per lane.
// MODE 1: Y_bf16 = relu(A H); MODE 2: += residual; MODE 3: Y_f32 = A H.
// ---------------------------------------------------------------------------
template<int LPC>
__device__ __forceinline__ void load_row(const u16* p, u32* u) {
    if constexpr (LPC == 8) {
        const uint4 t = *(const uint4*)p;
        u[0] = t.x; u[1] = t.y; u[2] = t.z; u[3] = t.w;
    } else {
        const uint2 t = *(const uint2*)p;
        u[0] = t.x; u[1] = t.y;
    }
}

template<int LPC>
__device__ __forceinline__ void fma_row(float v, const u32* u, float* a) {
    #pragma unroll
    for (int j = 0; j < LPC / 2; ++j) {
        a[2*j]   = fmaf(v, __uint_as_float(u[j] << 16),         a[2*j]);
        a[2*j+1] = fmaf(v, __uint_as_float(u[j] & 0xffff0000u), a[2*j+1]);
    }
}

template<int D, int MODE>
__global__ __launch_bounds__(256)
void spmm_csr(const int* __restrict__ offs, const int2* __restrict__ pce,
              const u16* __restrict__ Hb, void* __restrict__ Yv,
              const u16* __restrict__ Res)
{
    constexpr int LPC = D / 16;
    const int ln  = threadIdx.x & 15;
    const int row = blockIdx.x * 16 + (threadIdx.x >> 4);
    if (row >= NN) return;
    const int s = offs[row];
    const int t = offs[row + 1];
    const u16* hbase = Hb + ln * LPC;

    float a0[LPC], a1[LPC], a2[LPC], a3[LPC];
    #pragma unroll
    for (int j = 0; j < LPC; ++j) { a0[j] = 0.f; a1[j] = 0.f; a2[j] = 0.f; a3[j] = 0.f; }

    int e = s;
    for (; e + 3 < t; e += 4) {
        const int2 e0 = pce[e];
        const int2 e1 = pce[e + 1];
        const int2 e2 = pce[e + 2];
        const int2 e3 = pce[e + 3];
        u32 u0[LPC / 2], u1[LPC / 2], u2[LPC / 2], u3[LPC / 2];
        load_row<LPC>(hbase + (size_t)e0.x * D, u0);
        load_row<LPC>(hbase + (size_t)e1.x * D, u1);
        load_row<LPC>(hbase + (size_t)e2.x * D, u2);
        load_row<LPC>(hbase + (size_t)e3.x * D, u3);
        fma_row<LPC>(__int_as_float(e0.y), u0, a0);
        fma_row<LPC>(__int_as_float(e1.y), u1, a1);
        fma_row<LPC>(__int_as_float(e2.y), u2, a2);
        fma_row<LPC>(__int_as_float(e3.y), u3, a3);
    }
    for (; e < t; ++e) {
        const int2 e0 = pce[e];
        u32 u0[LPC / 2];
        load_row<LPC>(hbase + (size_t)e0.x * D, u0);
        fma_row<LPC>(__int_as_float(e0.y), u0, a0);
    }
    #pragma unroll
    for (int j = 0; j < LPC; ++j) a0[j] += a1[j] + a2[j] + a3[j];

    if constexpr (MODE == 3) {
        float* Y = (float*)Yv;
        *(float4*)(Y + (size_t)row * D + ln * LPC) =
            make_float4(a0[0], a0[1], a0[2], a0[3]);
    } else {
        if constexpr (MODE == 2) {
            u32 r[LPC / 2];
            load_row<LPC>(Res + (size_t)row * D + ln * LPC, r);
            #pragma unroll
            for (int j = 0; j < LPC / 2; ++j) {
                a0[2*j]   = fmaxf(a0[2*j],   0.f) + __uint_as_float(r[j] << 16);
                a0[2*j+1] = fmaxf(a0[2*j+1], 0.f) + __uint_as_float(r[j] & 0xffff0000u);
            }
        } else {
            #pragma unroll
            for (int j = 0; j < LPC; ++j) a0[j] = fmaxf(a0[j], 0.f);
        }
        u32 o[LPC / 2];
        #pragma unroll
        for (int j = 0; j < LPC / 2; ++j)
            o[j] = (u32)f2bf(a0[2*j]) | ((u32)f2bf(a0[2*j+1]) << 16);
        u16* Y = (u16*)Yv;
        if constexpr (LPC == 8)
            *(uint4*)(Y + (size_t)row * D + ln * LPC) = make_uint4(o[0], o[1], o[2], o[3]);
        else
            *(uint2*)(Y + (size_t)row * D + ln * LPC) = make_uint2(o[0], o[1]);
    }
}

extern "C" void kernel_launch(void* const* d_in, const int* in_sizes, int n_in,
                              void* d_out, int out_size, void* d_ws, size_t ws_size,
                              hipStream_t stream) {
    const float* x    = (const float*)d_in[0];
    const int*   erow = (const int*)  d_in[1];
    const int*   ecol = (const int*)  d_in[2];
    const float* eval = (const float*)d_in[3];
    const float* W0   = (const float*)d_in[4];
    const float* W1   = (const float*)d_in[5];
    const float* W2   = (const float*)d_in[6];
    float* out = (float*)d_out;

    char* p = (char*)d_ws;
    const size_t BUFB = (size_t)NN * 128 * sizeof(u16);   // 25.6 MB
    u16* tb   = (u16*)p;  p += BUFB;
    u16* h1b  = (u16*)p;  p += BUFB;
    u16* h2b  = (u16*)p;  p += BUFB;
    u16* w0b  = (u16*)p;  p += 128 * 128 * 2;
    u16* w1b  = (u16*)p;  p += 128 * 128 * 2;
    u16* w2b  = (u16*)p;  p += 64 * 128 * 2;
    int* bcur   = (int*)p; p += 256 * 4;
    int* bbase  = (int*)p; p += 256 * 4;
    int* offs   = (int*)p; p += ((size_t)PAD + 256) * 4;
    int2* part  = (int2*)p; p += (size_t)NBUCK * BCAP * 8;  // 16.06 MB
    int2* pce   = (int2*)p;                                 // 12.8 MB

    const dim3 blk(256);
    const int gemmBlocks  = (NN + 63) / 64;        // 1563
    const int spmmBlocks  = (NN + 15) / 16;        // 6250
    const int part1Blocks = (NE + EPB - 1) / EPB;  // 782

    // ---- CSR build ----
    hipMemsetAsync(bcur, 0, 256 * 4, stream);
    part1_kernel<<<part1Blocks, blk, 0, stream>>>(erow, ecol, eval, bcur, part);
    scanb_kernel<<<1, blk, 0, stream>>>(bcur, bbase);
    part2_kernel<<<NBUCK, blk, 0, stream>>>(bcur, bbase, part, offs, pce);
    wcvt_kernel <<<64, blk, 0, stream>>>(W0, W1, W2, w0b, w1b, w2b);

    // ---- layers ----
    gemm_mfma<128, true ><<<gemmBlocks, blk, 0, stream>>>(x,   w0b, tb, NN);
    spmm_csr<128, 1><<<spmmBlocks, blk, 0, stream>>>(offs, pce, tb, h1b, nullptr);
    gemm_mfma<128, false><<<gemmBlocks, blk, 0, stream>>>(h1b, w1b, tb, NN);
    spmm_csr<128, 2><<<spmmBlocks, blk, 0, stream>>>(offs, pce, tb, h2b, h1b);
    gemm_mfma<64,  false><<<gemmBlocks, blk, 0, stream>>>(h2b, w2b, tb, NN);
    spmm_csr<64, 3><<<spmmBlocks, blk, 0, stream>>>(offs, pce, tb, out, nullptr);
}

// Round 7
// 390.011 us; speedup vs baseline: 1.1148x; 1.1148x over previous
//
#include <hip/hip_runtime.h>

// GCN on MI355X (gfx950). n=100000, 1.6M edges, D 128/128/64.
// Round 7: GEMM fixed for scattered-fragment-load serialization:
//  - W pre-shuffled into MFMA B-fragment order in global (coalesced L1 bursts)
//  - A-tile staged via LDS with coalesced global reads; frags via ds_read_b128
// SpMM reverted to round-5 2-edge form (round-6 4-deep unroll regressed:
// memory path is throughput-saturated, extra MLP only cost occupancy).
// scanb folded into part2.

typedef unsigned int u32;
typedef unsigned short u16;
typedef __attribute__((ext_vector_type(8))) short bf16x8;
typedef __attribute__((ext_vector_type(4))) float f32x4;

constexpr int NN = 100000;
constexpr int NE = 1600000;
constexpr int PAD = 100352;            // 196 * 512
constexpr int NBUCK = 196;             // buckets of 512 rows
constexpr int BCAP = 10240;            // per-bucket capacity (mean 8163)
constexpr int EPB = 2048;              // edges per part1 block

__device__ __forceinline__ u16 f2bf(float f) {   // RNE round to bf16
    u32 x = __float_as_uint(f);
    x += 0x7fffu + ((x >> 16) & 1u);
    return (u16)(x >> 16);
}

// ---------------------------------------------------------------------------
// GEMM: C_bf16[n x DO] = H @ W^T, mfma_f32_16x16x32_bf16, fp32 accum.
// Wf is in B-fragment order: Wf[((ct*4+kc)*64+lane)*8+j] =
//   W[(ct*16+(lane&15))*128 + kc*32 + (lane>>4)*8 + j]  -> B-loads coalesced.
// A staged via LDS (coalesced global reads), frags read once per wave.
// LDS: sA (64 rows x 136 u16) reused as sC for the coalescing epilogue.
// ---------------------------------------------------------------------------
template<int DO, bool FP32IN>
__global__ __launch_bounds__(256)
void gemm_mfma(const void* __restrict__ Hin, const u16* __restrict__ Wf,
               u16* __restrict__ Cb, int n)
{
    constexpr int RS   = 136;          // A row stride (elems); 272 B, 16B-aligned
    constexpr int PADW = DO + 8;       // C row stride (elems)
    __shared__ u16 smem[64 * 136];     // sA and sC (both <= 17408 B)
    u16* sA = smem;
    u16* sC = smem;

    const int tid  = threadIdx.x;
    const int w    = tid >> 6;
    const int lane = tid & 63;
    const int m    = lane & 15;
    const int q    = lane >> 4;
    const int rowBase = blockIdx.x * 64;

    // ---- stage A tile (64 rows x 128) into LDS, coalesced ----
    if (FP32IN) {
        const float* H = (const float*)Hin;
        #pragma unroll
        for (int i = 0; i < 8; ++i) {
            const int g = (i * 256 + tid) * 4;      // elem index in tile
            const int r = g >> 7, c = g & 127;
            float4 v = make_float4(0.f, 0.f, 0.f, 0.f);
            if (rowBase + r < n) v = *(const float4*)(H + (size_t)(rowBase + r) * 128 + c);
            u16* d = &sA[r * RS + c];
            d[0] = f2bf(v.x); d[1] = f2bf(v.y); d[2] = f2bf(v.z); d[3] = f2bf(v.w);
        }
    } else {
        const u16* H = (const u16*)Hin;
        #pragma unroll
        for (int i = 0; i < 4; ++i) {
            const int g = (i * 256 + tid) * 8;
            const int r = g >> 7, c = g & 127;
            uint4 v = make_uint4(0, 0, 0, 0);
            if (rowBase + r < n) v = *(const uint4*)(H + (size_t)(rowBase + r) * 128 + c);
            *(uint4*)&sA[r * RS + c] = v;
        }
    }
    __syncthreads();

    // ---- A-fragments: 4 ds_read_b128 per lane, held in registers ----
    bf16x8 afrag[4];
    #pragma unroll
    for (int kc = 0; kc < 4; ++kc)
        afrag[kc] = *(const bf16x8*)&sA[(w * 16 + m) * RS + kc * 32 + q * 8];
    __syncthreads();   // sA consumed; smem becomes sC

    // ---- MFMA loop; B from fragment-ordered global (L1-hot, coalesced) ----
    #pragma unroll
    for (int ct = 0; ct < DO / 16; ++ct) {
        f32x4 acc = {0.f, 0.f, 0.f, 0.f};
        #pragma unroll
        for (int kc = 0; kc < 4; ++kc) {
            const bf16x8 b = *(const bf16x8*)(Wf + (((ct * 4 + kc) * 64) + lane) * 8);
            acc = __builtin_amdgcn_mfma_f32_16x16x32_bf16(afrag[kc], b, acc, 0, 0, 0);
        }
        #pragma unroll
        for (int r = 0; r < 4; ++r)
            sC[(w * 16 + q * 4 + r) * PADW + ct * 16 + m] = f2bf(acc[r]);
    }
    __syncthreads();

    // ---- coalesced store: per-wave 16 rows x DO ----
    const int g    = lane >> 2;
    const int cb   = (lane & 3) * (DO / 4);
    const int grow = rowBase + w * 16 + g;
    if (grow < n) {
        #pragma unroll
        for (int i = 0; i < DO / 32; ++i) {
            const int4 v = *(const int4*)&sC[(w * 16 + g) * PADW + cb + i * 8];
            *(int4*)(Cb + (size_t)grow * DO + cb + i * 8) = v;
        }
    }
}

// ---------------------------------------------------------------------------
// Weight fp32 -> bf16 in B-fragment order. dest index d in [0, DO*128):
// j=d&7, lane=(d>>3)&63, kc=(d>>9)&3, ct=d>>11.
// ---------------------------------------------------------------------------
__device__ __forceinline__ void wfrag_one(const float* __restrict__ W,
                                          u16* __restrict__ Wf, int total, int i)
{
    if (i < total) {
        const int j    = i & 7;
        const int lane = (i >> 3) & 63;
        const int kc   = (i >> 9) & 3;
        const int ct   = i >> 11;
        const int src  = (ct * 16 + (lane & 15)) * 128 + kc * 32 + (lane >> 4) * 8 + j;
        Wf[i] = f2bf(W[src]);
    }
}

__global__ __launch_bounds__(256)
void wcvt_kernel(const float* __restrict__ W0, const float* __restrict__ W1,
                 const float* __restrict__ W2, u16* __restrict__ wf0,
                 u16* __restrict__ wf1, u16* __restrict__ wf2)
{
    const int i = blockIdx.x * 256 + threadIdx.x;
    wfrag_one(W0, wf0, 128 * 128, i);
    wfrag_one(W1, wf1, 128 * 128, i);
    wfrag_one(W2, wf2, 64 * 128, i);
}

// ---------------------------------------------------------------------------
// part1: bucket partition, streaming two-pass (low VGPR, no global per-row
// atomics).
// ---------------------------------------------------------------------------
__global__ __launch_bounds__(256)
void part1_kernel(const int* __restrict__ erow, const int* __restrict__ ecol,
                  const float* __restrict__ eval, int* __restrict__ bcur,
                  int2* __restrict__ part)
{
    __shared__ int shist[NBUCK];
    __shared__ int sbase[NBUCK];
    const int tid = threadIdx.x;
    for (int i = tid; i < NBUCK; i += 256) shist[i] = 0;
    __syncthreads();

    const int base = blockIdx.x * EPB;
    #pragma unroll
    for (int j = 0; j < EPB / 256; ++j) {
        const int e = base + j * 256 + tid;
        if (e < NE) atomicAdd(&shist[erow[e] >> 9], 1);
    }
    __syncthreads();
    for (int i = tid; i < NBUCK; i += 256) {
        const int c = shist[i];
        sbase[i] = c ? atomicAdd(&bcur[i], c) : 0;
        shist[i] = 0;
    }
    __syncthreads();
    #pragma unroll
    for (int j = 0; j < EPB / 256; ++j) {
        const int e = base + j * 256 + tid;
        if (e < NE) {
            const int r = erow[e];
            const int b = r >> 9;
            const int rk = atomicAdd(&shist[b], 1);
            part[b * BCAP + sbase[b] + rk] =
                make_int2(((r & 511) << 17) | ecol[e], __float_as_int(eval[e]));
        }
    }
}

// ---------------------------------------------------------------------------
// part2: local scan of 196 bucket totals (folds old scanb) -> per-bucket row
// histogram + 512-wide LDS scan -> offs; LDS-cursor scatter into the
// bucket's contiguous CSR slice.
// ---------------------------------------------------------------------------
__global__ __launch_bounds__(256)
void part2_kernel(const int* __restrict__ bcur, const int2* __restrict__ part,
                  int* __restrict__ offs, int2* __restrict__ pce)
{
    __shared__ int scnt[512];
    __shared__ int sdata[256];
    __shared__ int rowoff[512];
    const int b = blockIdx.x;
    const int tid = threadIdx.x;

    // bucket-prefix: scan bcur[0..NBUCK) locally, keep exclusive prefix at b.
    const int bv = (tid < NBUCK) ? bcur[tid] : 0;
    sdata[tid] = bv;
    __syncthreads();
    #pragma unroll
    for (int off = 1; off < 256; off <<= 1) {
        const int val = (tid >= off) ? sdata[tid - off] : 0;
        __syncthreads();
        sdata[tid] += val;
        __syncthreads();
    }
    const int gb = (b > 0) ? sdata[b - 1] : 0;   // exclusive prefix for bucket b
    const int cnt = bcur[b];
    __syncthreads();

    scnt[tid] = 0; scnt[tid + 256] = 0;
    __syncthreads();

    const int2* src = part + (size_t)b * BCAP;
    for (int i = tid; i < cnt; i += 256)
        atomicAdd(&scnt[((u32)src[i].x) >> 17], 1);
    __syncthreads();

    const int c0 = scnt[2 * tid];
    const int c1 = scnt[2 * tid + 1];
    const int tsum = c0 + c1;
    sdata[tid] = tsum;
    __syncthreads();
    #pragma unroll
    for (int off = 1; off < 256; off <<= 1) {
        const int val = (tid >= off) ? sdata[tid - off] : 0;
        __syncthreads();
        sdata[tid] += val;
        __syncthreads();
    }
    const int excl = sdata[tid] - tsum;
    rowoff[2 * tid]     = gb + excl;
    rowoff[2 * tid + 1] = gb + excl + c0;
    __syncthreads();

    offs[b * 512 + tid]       = rowoff[tid];
    offs[b * 512 + 256 + tid] = rowoff[tid + 256];
    __syncthreads();

    for (int i = tid; i < cnt; i += 256) {
        const int2 ev = src[i];
        const int rl = ((u32)ev.x) >> 17;
        const int pos = atomicAdd(&rowoff[rl], 1);
        pce[pos] = make_int2(ev.x & 0x1FFFF, ev.y);
    }
}

// ---------------------------------------------------------------------------
// CSR SpMM over bf16 features, fp32 accumulate. 16 lanes/row, 16 rows/block.
// 2-edge unroll (round-5 form; memory path saturates, more MLP regressed).
// MODE 1: Y_bf16 = relu(A H); MODE 2: += residual; MODE 3: Y_f32 = A H.
// ---------------------------------------------------------------------------
template<int LPC>
__device__ __forceinline__ void load_row(const u16* p, u32* u) {
    if constexpr (LPC == 8) {
        const uint4 t = *(const uint4*)p;
        u[0] = t.x; u[1] = t.y; u[2] = t.z; u[3] = t.w;
    } else {
        const uint2 t = *(const uint2*)p;
        u[0] = t.x; u[1] = t.y;
    }
}

template<int LPC>
__device__ __forceinline__ void fma_row(float v, const u32* u, float* a) {
    #pragma unroll
    for (int j = 0; j < LPC / 2; ++j) {
        a[2*j]   = fmaf(v, __uint_as_float(u[j] << 16),         a[2*j]);
        a[2*j+1] = fmaf(v, __uint_as_float(u[j] & 0xffff0000u), a[2*j+1]);
    }
}

template<int D, int MODE>
__global__ __launch_bounds__(256)
void spmm_csr(const int* __restrict__ offs, const int2* __restrict__ pce,
              const u16* __restrict__ Hb, void* __restrict__ Yv,
              const u16* __restrict__ Res)
{
    constexpr int LPC = D / 16;
    const int ln  = threadIdx.x & 15;
    const int row = blockIdx.x * 16 + (threadIdx.x >> 4);
    if (row >= NN) return;
    const int s = offs[row];
    const int t = offs[row + 1];
    const u16* hbase = Hb + ln * LPC;

    float a0[LPC], a1[LPC];
    #pragma unroll
    for (int j = 0; j < LPC; ++j) { a0[j] = 0.f; a1[j] = 0.f; }

    int e = s;
    for (; e + 1 < t; e += 2) {
        const int2 e0 = pce[e];
        const int2 e1 = pce[e + 1];
        u32 u0[LPC / 2], u1[LPC / 2];
        load_row<LPC>(hbase + (size_t)e0.x * D, u0);
        load_row<LPC>(hbase + (size_t)e1.x * D, u1);
        fma_row<LPC>(__int_as_float(e0.y), u0, a0);
        fma_row<LPC>(__int_as_float(e1.y), u1, a1);
    }
    if (e < t) {
        const int2 e0 = pce[e];
        u32 u0[LPC / 2];
        load_row<LPC>(hbase + (size_t)e0.x * D, u0);
        fma_row<LPC>(__int_as_float(e0.y), u0, a0);
    }
    #pragma unroll
    for (int j = 0; j < LPC; ++j) a0[j] += a1[j];

    if constexpr (MODE == 3) {
        float* Y = (float*)Yv;
        *(float4*)(Y + (size_t)row * D + ln * LPC) =
            make_float4(a0[0], a0[1], a0[2], a0[3]);
    } else {
        if constexpr (MODE == 2) {
            u32 r[LPC / 2];
            load_row<LPC>(Res + (size_t)row * D + ln * LPC, r);
            #pragma unroll
            for (int j = 0; j < LPC / 2; ++j) {
                a0[2*j]   = fmaxf(a0[2*j],   0.f) + __uint_as_float(r[j] << 16);
                a0[2*j+1] = fmaxf(a0[2*j+1], 0.f) + __uint_as_float(r[j] & 0xffff0000u);
            }
        } else {
            #pragma unroll
            for (int j = 0; j < LPC; ++j) a0[j] = fmaxf(a0[j], 0.f);
        }
        u32 o[LPC / 2];
        #pragma unroll
        for (int j = 0; j < LPC / 2; ++j)
            o[j] = (u32)f2bf(a0[2*j]) | ((u32)f2bf(a0[2*j+1]) << 16);
        u16* Y = (u16*)Yv;
        if constexpr (LPC == 8)
            *(uint4*)(Y + (size_t)row * D + ln * LPC) = make_uint4(o[0], o[1], o[2], o[3]);
        else
            *(uint2*)(Y + (size_t)row * D + ln * LPC) = make_uint2(o[0], o[1]);
    }
}

extern "C" void kernel_launch(void* const* d_in, const int* in_sizes, int n_in,
                              void* d_out, int out_size, void* d_ws, size_t ws_size,
                              hipStream_t stream) {
    const float* x    = (const float*)d_in[0];
    const int*   erow = (const int*)  d_in[1];
    const int*   ecol = (const int*)  d_in[2];
    const float* eval = (const float*)d_in[3];
    const float* W0   = (const float*)d_in[4];
    const float* W1   = (const float*)d_in[5];
    const float* W2   = (const float*)d_in[6];
    float* out = (float*)d_out;

    char* p = (char*)d_ws;
    const size_t BUFB = (size_t)NN * 128 * sizeof(u16);   // 25.6 MB
    u16* tb   = (u16*)p;  p += BUFB;
    u16* h1b  = (u16*)p;  p += BUFB;
    u16* h2b  = (u16*)p;  p += BUFB;
    u16* wf0  = (u16*)p;  p += 128 * 128 * 2;
    u16* wf1  = (u16*)p;  p += 128 * 128 * 2;
    u16* wf2  = (u16*)p;  p += 64 * 128 * 2;
    int* bcur   = (int*)p; p += 256 * 4;
    int* offs   = (int*)p; p += ((size_t)PAD + 256) * 4;
    int2* part  = (int2*)p; p += (size_t)NBUCK * BCAP * 8;  // 16.06 MB
    int2* pce   = (int2*)p;                                 // 12.8 MB

    const dim3 blk(256);
    const int gemmBlocks  = (NN + 63) / 64;        // 1563
    const int spmmBlocks  = (NN + 15) / 16;        // 6250
    const int part1Blocks = (NE + EPB - 1) / EPB;  // 782

    // ---- CSR build + weight fragment-reorder ----
    hipMemsetAsync(bcur, 0, 256 * 4, stream);
    part1_kernel<<<part1Blocks, blk, 0, stream>>>(erow, ecol, eval, bcur, part);
    part2_kernel<<<NBUCK, blk, 0, stream>>>(bcur, part, offs, pce);
    wcvt_kernel <<<64, blk, 0, stream>>>(W0, W1, W2, wf0, wf1, wf2);

    // ---- layers ----
    gemm_mfma<128, true ><<<gemmBlocks, blk, 0, stream>>>(x,   wf0, tb, NN);
    spmm_csr<128, 1><<<spmmBlocks, blk, 0, stream>>>(offs, pce, tb, h1b, nullptr);
    gemm_mfma<128, false><<<gemmBlocks, blk, 0, stream>>>(h1b, wf1, tb, NN);
    spmm_csr<128, 2><<<spmmBlocks, blk, 0, stream>>>(offs, pce, tb, h2b, h1b);
    gemm_mfma<64,  false><<<gemmBlocks, blk, 0, stream>>>(h2b, wf2, tb, NN);
    spmm_csr<64, 3><<<spmmBlocks, blk, 0, stream>>>(offs, pce, tb, out, nullptr);
}

// Round 8
// 364.578 us; speedup vs baseline: 1.1926x; 1.0698x over previous
//
#include <hip/hip_runtime.h>

// GCN on MI355X (gfx950). n=100000, 1.6M edges, D 128/128/64.
// Round 8: fuse SpMM with the consuming GEMM. Each SpMM block produces 16
// complete rows of A*t — exactly one MFMA A-tile — so relu(+residual),
// round to bf16, bounce through LDS, and run mfma_16x16x32_bf16 against the
// fragment-ordered W in the same kernel:
//   F1 = spmm1+gemm1 (writes h1 for the residual AND t1 = h1 W1^T)
//   F2 = spmm2+gemm2 (h2 never materialized; writes t2 = h2 W2^T)
// gemm0 (dense input) and the final spmm64 stay standalone.

typedef unsigned int u32;
typedef unsigned short u16;
typedef __attribute__((ext_vector_type(8))) short bf16x8;
typedef __attribute__((ext_vector_type(4))) float f32x4;

constexpr int NN = 100000;
constexpr int NE = 1600000;
constexpr int PAD = 100352;            // 196 * 512
constexpr int NBUCK = 196;             // buckets of 512 rows
constexpr int BCAP = 10240;            // per-bucket capacity (mean 8163)
constexpr int EPB = 2048;              // edges per part1 block

__device__ __forceinline__ u16 f2bf(float f) {   // RNE round to bf16
    u32 x = __float_as_uint(f);
    x += 0x7fffu + ((x >> 16) & 1u);
    return (u16)(x >> 16);
}

// ---------------------------------------------------------------------------
// Standalone GEMM (layer 0 only): C_bf16[n x DO] = H @ W^T.
// Wf in B-fragment order; A staged via LDS; coalesced epilogue.
// ---------------------------------------------------------------------------
template<int DO, bool FP32IN>
__global__ __launch_bounds__(256)
void gemm_mfma(const void* __restrict__ Hin, const u16* __restrict__ Wf,
               u16* __restrict__ Cb, int n)
{
    constexpr int RS   = 136;
    constexpr int PADW = DO + 8;
    __shared__ u16 smem[64 * 136];
    u16* sA = smem;
    u16* sC = smem;

    const int tid  = threadIdx.x;
    const int w    = tid >> 6;
    const int lane = tid & 63;
    const int m    = lane & 15;
    const int q    = lane >> 4;
    const int rowBase = blockIdx.x * 64;

    if (FP32IN) {
        const float* H = (const float*)Hin;
        #pragma unroll
        for (int i = 0; i < 8; ++i) {
            const int g = (i * 256 + tid) * 4;
            const int r = g >> 7, c = g & 127;
            float4 v = make_float4(0.f, 0.f, 0.f, 0.f);
            if (rowBase + r < n) v = *(const float4*)(H + (size_t)(rowBase + r) * 128 + c);
            u16* d = &sA[r * RS + c];
            d[0] = f2bf(v.x); d[1] = f2bf(v.y); d[2] = f2bf(v.z); d[3] = f2bf(v.w);
        }
    } else {
        const u16* H = (const u16*)Hin;
        #pragma unroll
        for (int i = 0; i < 4; ++i) {
            const int g = (i * 256 + tid) * 8;
            const int r = g >> 7, c = g & 127;
            uint4 v = make_uint4(0, 0, 0, 0);
            if (rowBase + r < n) v = *(const uint4*)(H + (size_t)(rowBase + r) * 128 + c);
            *(uint4*)&sA[r * RS + c] = v;
        }
    }
    __syncthreads();

    bf16x8 afrag[4];
    #pragma unroll
    for (int kc = 0; kc < 4; ++kc)
        afrag[kc] = *(const bf16x8*)&sA[(w * 16 + m) * RS + kc * 32 + q * 8];
    __syncthreads();

    #pragma unroll
    for (int ct = 0; ct < DO / 16; ++ct) {
        f32x4 acc = {0.f, 0.f, 0.f, 0.f};
        #pragma unroll
        for (int kc = 0; kc < 4; ++kc) {
            const bf16x8 b = *(const bf16x8*)(Wf + (((ct * 4 + kc) * 64) + lane) * 8);
            acc = __builtin_amdgcn_mfma_f32_16x16x32_bf16(afrag[kc], b, acc, 0, 0, 0);
        }
        #pragma unroll
        for (int r = 0; r < 4; ++r)
            sC[(w * 16 + q * 4 + r) * PADW + ct * 16 + m] = f2bf(acc[r]);
    }
    __syncthreads();

    const int g    = lane >> 2;
    const int cb   = (lane & 3) * (DO / 4);
    const int grow = rowBase + w * 16 + g;
    if (grow < n) {
        #pragma unroll
        for (int i = 0; i < DO / 32; ++i) {
            const int4 v = *(const int4*)&sC[(w * 16 + g) * PADW + cb + i * 8];
            *(int4*)(Cb + (size_t)grow * DO + cb + i * 8) = v;
        }
    }
}

// ---------------------------------------------------------------------------
// Weight fp32 -> bf16 in B-fragment order.
// ---------------------------------------------------------------------------
__device__ __forceinline__ void wfrag_one(const float* __restrict__ W,
                                          u16* __restrict__ Wf, int total, int i)
{
    if (i < total) {
        const int j    = i & 7;
        const int lane = (i >> 3) & 63;
        const int kc   = (i >> 9) & 3;
        const int ct   = i >> 11;
        const int src  = (ct * 16 + (lane & 15)) * 128 + kc * 32 + (lane >> 4) * 8 + j;
        Wf[i] = f2bf(W[src]);
    }
}

__global__ __launch_bounds__(256)
void wcvt_kernel(const float* __restrict__ W0, const float* __restrict__ W1,
                 const float* __restrict__ W2, u16* __restrict__ wf0,
                 u16* __restrict__ wf1, u16* __restrict__ wf2)
{
    const int i = blockIdx.x * 256 + threadIdx.x;
    wfrag_one(W0, wf0, 128 * 128, i);
    wfrag_one(W1, wf1, 128 * 128, i);
    wfrag_one(W2, wf2, 64 * 128, i);
}

// ---------------------------------------------------------------------------
// part1: bucket partition, streaming two-pass.
// ---------------------------------------------------------------------------
__global__ __launch_bounds__(256)
void part1_kernel(const int* __restrict__ erow, const int* __restrict__ ecol,
                  const float* __restrict__ eval, int* __restrict__ bcur,
                  int2* __restrict__ part)
{
    __shared__ int shist[NBUCK];
    __shared__ int sbase[NBUCK];
    const int tid = threadIdx.x;
    for (int i = tid; i < NBUCK; i += 256) shist[i] = 0;
    __syncthreads();

    const int base = blockIdx.x * EPB;
    #pragma unroll
    for (int j = 0; j < EPB / 256; ++j) {
        const int e = base + j * 256 + tid;
        if (e < NE) atomicAdd(&shist[erow[e] >> 9], 1);
    }
    __syncthreads();
    for (int i = tid; i < NBUCK; i += 256) {
        const int c = shist[i];
        sbase[i] = c ? atomicAdd(&bcur[i], c) : 0;
        shist[i] = 0;
    }
    __syncthreads();
    #pragma unroll
    for (int j = 0; j < EPB / 256; ++j) {
        const int e = base + j * 256 + tid;
        if (e < NE) {
            const int r = erow[e];
            const int b = r >> 9;
            const int rk = atomicAdd(&shist[b], 1);
            part[b * BCAP + sbase[b] + rk] =
                make_int2(((r & 511) << 17) | ecol[e], __float_as_int(eval[e]));
        }
    }
}

// ---------------------------------------------------------------------------
// part2: local bucket-prefix scan + per-bucket row histogram + 512-wide
// LDS scan -> offs; LDS-cursor scatter into contiguous CSR slice.
// ---------------------------------------------------------------------------
__global__ __launch_bounds__(256)
void part2_kernel(const int* __restrict__ bcur, const int2* __restrict__ part,
                  int* __restrict__ offs, int2* __restrict__ pce)
{
    __shared__ int scnt[512];
    __shared__ int sdata[256];
    __shared__ int rowoff[512];
    const int b = blockIdx.x;
    const int tid = threadIdx.x;

    const int bv = (tid < NBUCK) ? bcur[tid] : 0;
    sdata[tid] = bv;
    __syncthreads();
    #pragma unroll
    for (int off = 1; off < 256; off <<= 1) {
        const int val = (tid >= off) ? sdata[tid - off] : 0;
        __syncthreads();
        sdata[tid] += val;
        __syncthreads();
    }
    const int gb = (b > 0) ? sdata[b - 1] : 0;
    const int cnt = bcur[b];
    __syncthreads();

    scnt[tid] = 0; scnt[tid + 256] = 0;
    __syncthreads();

    const int2* src = part + (size_t)b * BCAP;
    for (int i = tid; i < cnt; i += 256)
        atomicAdd(&scnt[((u32)src[i].x) >> 17], 1);
    __syncthreads();

    const int c0 = scnt[2 * tid];
    const int c1 = scnt[2 * tid + 1];
    const int tsum = c0 + c1;
    sdata[tid] = tsum;
    __syncthreads();
    #pragma unroll
    for (int off = 1; off < 256; off <<= 1) {
        const int val = (tid >= off) ? sdata[tid - off] : 0;
        __syncthreads();
        sdata[tid] += val;
        __syncthreads();
    }
    const int excl = sdata[tid] - tsum;
    rowoff[2 * tid]     = gb + excl;
    rowoff[2 * tid + 1] = gb + excl + c0;
    __syncthreads();

    offs[b * 512 + tid]       = rowoff[tid];
    offs[b * 512 + 256 + tid] = rowoff[tid + 256];
    __syncthreads();

    for (int i = tid; i < cnt; i += 256) {
        const int2 ev = src[i];
        const int rl = ((u32)ev.x) >> 17;
        const int pos = atomicAdd(&rowoff[rl], 1);
        pce[pos] = make_int2(ev.x & 0x1FFFF, ev.y);
    }
}

// ---------------------------------------------------------------------------
// Gather helpers (bf16 rows, fp32 accumulate).
// ---------------------------------------------------------------------------
template<int LPC>
__device__ __forceinline__ void load_row(const u16* p, u32* u) {
    if constexpr (LPC == 8) {
        const uint4 t = *(const uint4*)p;
        u[0] = t.x; u[1] = t.y; u[2] = t.z; u[3] = t.w;
    } else {
        const uint2 t = *(const uint2*)p;
        u[0] = t.x; u[1] = t.y;
    }
}

template<int LPC>
__device__ __forceinline__ void fma_row(float v, const u32* u, float* a) {
    #pragma unroll
    for (int j = 0; j < LPC / 2; ++j) {
        a[2*j]   = fmaf(v, __uint_as_float(u[j] << 16),         a[2*j]);
        a[2*j+1] = fmaf(v, __uint_as_float(u[j] & 0xffff0000u), a[2*j+1]);
    }
}

// ---------------------------------------------------------------------------
// Fused SpMM+GEMM: block = 16 rows. Phase 1: CSR gather (16 lanes/row,
// 2-edge unroll) -> relu (+residual MODE 2) -> bf16 into LDS A-tile
// (MODE 1 also writes the relu'd rows to Hout for the later residual).
// Phase 2: one MFMA A-tile (16x128) x Wf -> C (16xDO) via LDS, coalesced.
// ---------------------------------------------------------------------------
template<int DO, int MODE>
__global__ __launch_bounds__(256)
void spmm_gemm(const int* __restrict__ offs, const int2* __restrict__ pce,
               const u16* __restrict__ Hb, const u16* __restrict__ Wf,
               const u16* __restrict__ Res, u16* __restrict__ Cb,
               u16* __restrict__ Hout)
{
    constexpr int RS   = 136;          // A-tile row stride (u16)
    constexpr int PADW = DO + 8;       // C-tile row stride (u16)
    __shared__ u16 smem[16 * 136];     // sA then sC
    const int tid = threadIdx.x;
    const int ln  = tid & 15;
    const int rl  = tid >> 4;
    const int row = blockIdx.x * 16 + rl;

    // ---- phase 1: gather A*t rows ----
    const int s = offs[row];
    const int t = offs[row + 1];
    const u16* hbase = Hb + ln * 8;

    float a0[8], a1[8];
    #pragma unroll
    for (int j = 0; j < 8; ++j) { a0[j] = 0.f; a1[j] = 0.f; }

    int e = s;
    for (; e + 1 < t; e += 2) {
        const int2 e0 = pce[e];
        const int2 e1 = pce[e + 1];
        u32 u0[4], u1[4];
        load_row<8>(hbase + (size_t)e0.x * 128, u0);
        load_row<8>(hbase + (size_t)e1.x * 128, u1);
        fma_row<8>(__int_as_float(e0.y), u0, a0);
        fma_row<8>(__int_as_float(e1.y), u1, a1);
    }
    if (e < t) {
        const int2 e0 = pce[e];
        u32 u0[4];
        load_row<8>(hbase + (size_t)e0.x * 128, u0);
        fma_row<8>(__int_as_float(e0.y), u0, a0);
    }
    #pragma unroll
    for (int j = 0; j < 8; ++j) a0[j] = fmaxf(a0[j] + a1[j], 0.f);

    if constexpr (MODE == 2) {          // h2 = relu(A t1) + h1
        u32 r[4];
        load_row<8>(Res + (size_t)row * 128 + ln * 8, r);
        #pragma unroll
        for (int j = 0; j < 4; ++j) {
            a0[2*j]   += __uint_as_float(r[j] << 16);
            a0[2*j+1] += __uint_as_float(r[j] & 0xffff0000u);
        }
    }
    u32 o[4];
    #pragma unroll
    for (int j = 0; j < 4; ++j)
        o[j] = (u32)f2bf(a0[2*j]) | ((u32)f2bf(a0[2*j+1]) << 16);
    const uint4 packed = make_uint4(o[0], o[1], o[2], o[3]);
    *(uint4*)&smem[rl * RS + ln * 8] = packed;
    if constexpr (MODE == 1)
        *(uint4*)(Hout + (size_t)row * 128 + ln * 8) = packed;
    __syncthreads();

    // ---- phase 2: MFMA 16x128 A-tile against Wf ----
    constexpr int TPW = DO / 64;        // col-tiles per wave (2 for 128, 1 for 64)
    const int w    = tid >> 6;
    const int lane = tid & 63;
    const int m    = lane & 15;
    const int q    = lane >> 4;

    bf16x8 afrag[4];
    #pragma unroll
    for (int kc = 0; kc < 4; ++kc)
        afrag[kc] = *(const bf16x8*)&smem[m * RS + kc * 32 + q * 8];

    f32x4 acc[TPW];
    #pragma unroll
    for (int tw = 0; tw < TPW; ++tw) {
        const int ct = w * TPW + tw;
        acc[tw] = (f32x4){0.f, 0.f, 0.f, 0.f};
        #pragma unroll
        for (int kc = 0; kc < 4; ++kc) {
            const bf16x8 b = *(const bf16x8*)(Wf + (((ct * 4 + kc) * 64) + lane) * 8);
            acc[tw] = __builtin_amdgcn_mfma_f32_16x16x32_bf16(afrag[kc], b, acc[tw], 0, 0, 0);
        }
    }
    __syncthreads();   // all A-frag reads done; smem becomes sC

    #pragma unroll
    for (int tw = 0; tw < TPW; ++tw) {
        const int ct = w * TPW + tw;
        #pragma unroll
        for (int r = 0; r < 4; ++r)
            smem[(q * 4 + r) * PADW + ct * 16 + m] = f2bf(acc[tw][r]);
    }
    __syncthreads();

    // ---- coalesced C store: 16 rows x DO (contiguous per block) ----
    if (DO == 128 || tid < 128) {
        const int g = tid * 8;
        const int r = g / DO;
        const int c = g % DO;
        const int4 v = *(const int4*)&smem[r * PADW + c];
        *(int4*)(Cb + ((size_t)blockIdx.x * 16 + r) * DO + c) = v;
    }
}

// ---------------------------------------------------------------------------
// Final CSR SpMM (layer 3): gather t2 (D=64), write fp32 out.
// ---------------------------------------------------------------------------
__global__ __launch_bounds__(256)
void spmm_out(const int* __restrict__ offs, const int2* __restrict__ pce,
              const u16* __restrict__ Hb, float* __restrict__ Y)
{
    const int ln  = threadIdx.x & 15;
    const int row = blockIdx.x * 16 + (threadIdx.x >> 4);
    if (row >= NN) return;
    const int s = offs[row];
    const int t = offs[row + 1];
    const u16* hbase = Hb + ln * 4;

    float a0[4], a1[4];
    #pragma unroll
    for (int j = 0; j < 4; ++j) { a0[j] = 0.f; a1[j] = 0.f; }

    int e = s;
    for (; e + 1 < t; e += 2) {
        const int2 e0 = pce[e];
        const int2 e1 = pce[e + 1];
        u32 u0[2], u1[2];
        load_row<4>(hbase + (size_t)e0.x * 64, u0);
        load_row<4>(hbase + (size_t)e1.x * 64, u1);
        fma_row<4>(__int_as_float(e0.y), u0, a0);
        fma_row<4>(__int_as_float(e1.y), u1, a1);
    }
    if (e < t) {
        const int2 e0 = pce[e];
        u32 u0[2];
        load_row<4>(hbase + (size_t)e0.x * 64, u0);
        fma_row<4>(__int_as_float(e0.y), u0, a0);
    }
    #pragma unroll
    for (int j = 0; j < 4; ++j) a0[j] += a1[j];
    *(float4*)(Y + (size_t)row * 64 + ln * 4) = make_float4(a0[0], a0[1], a0[2], a0[3]);
}

extern "C" void kernel_launch(void* const* d_in, const int* in_sizes, int n_in,
                              void* d_out, int out_size, void* d_ws, size_t ws_size,
                              hipStream_t stream) {
    const float* x    = (const float*)d_in[0];
    const int*   erow = (const int*)  d_in[1];
    const int*   ecol = (const int*)  d_in[2];
    const float* eval = (const float*)d_in[3];
    const float* W0   = (const float*)d_in[4];
    const float* W1   = (const float*)d_in[5];
    const float* W2   = (const float*)d_in[6];
    float* out = (float*)d_out;

    char* p = (char*)d_ws;
    const size_t BUFB = (size_t)NN * 128 * sizeof(u16);   // 25.6 MB
    u16* t0b  = (u16*)p;  p += BUFB;     // t0; reused for t2 (t0 dead by then)
    u16* t1b  = (u16*)p;  p += BUFB;
    u16* h1b  = (u16*)p;  p += BUFB;
    u16* wf0  = (u16*)p;  p += 128 * 128 * 2;
    u16* wf1  = (u16*)p;  p += 128 * 128 * 2;
    u16* wf2  = (u16*)p;  p += 64 * 128 * 2;
    int* bcur   = (int*)p; p += 256 * 4;
    int* offs   = (int*)p; p += ((size_t)PAD + 256) * 4;
    int2* part  = (int2*)p; p += (size_t)NBUCK * BCAP * 8;  // 16.06 MB
    int2* pce   = (int2*)p;                                 // 12.8 MB

    const dim3 blk(256);
    const int gemmBlocks  = (NN + 63) / 64;        // 1563
    const int rowBlocks   = NN / 16;               // 6250 (16 | NN)
    const int part1Blocks = (NE + EPB - 1) / EPB;  // 782

    // ---- CSR build + weight fragment-reorder ----
    hipMemsetAsync(bcur, 0, 256 * 4, stream);
    part1_kernel<<<part1Blocks, blk, 0, stream>>>(erow, ecol, eval, bcur, part);
    part2_kernel<<<NBUCK, blk, 0, stream>>>(bcur, part, offs, pce);
    wcvt_kernel <<<64, blk, 0, stream>>>(W0, W1, W2, wf0, wf1, wf2);

    // ---- layers ----
    // t0 = x @ W0^T
    gemm_mfma<128, true><<<gemmBlocks, blk, 0, stream>>>(x, wf0, t0b, NN);
    // h1 = relu(A t0) [-> h1b]; t1 = h1 @ W1^T
    spmm_gemm<128, 1><<<rowBlocks, blk, 0, stream>>>(offs, pce, t0b, wf1, nullptr, t1b, h1b);
    // h2 = relu(A t1) + h1; t2 = h2 @ W2^T  (h2 not materialized; t2 -> t0b)
    spmm_gemm<64, 2><<<rowBlocks, blk, 0, stream>>>(offs, pce, t1b, wf2, h1b, t0b, nullptr);
    // out = A t2
    spmm_out<<<rowBlocks, blk, 0, stream>>>(offs, pce, t0b, out);
}

// Round 9
// 356.520 us; speedup vs baseline: 1.2195x; 1.0226x over previous
//
#include <hip/hip_runtime.h>

// GCN on MI355X (gfx950). n=100000, 1.6M edges, D 128/128/64.
// Round 9: merge the data-independent part1 (edge bucket partition) and
// gemm0 (x @ W0^T) into ONE dispatch (branch on blockIdx) for intra-
// dispatch overlap: part1 is LDS-atomic/scatter bound, gemm0 is VMEM/MFMA
// bound. EPB 2048->4096 (longer per-bucket write runs). bcur zeroing folded
// into wcvt. Pipeline: wcvt -> K1[part1||gemm0] -> part2 -> F1 -> F2 ->
// spmm_out  (6 dispatches).

typedef unsigned int u32;
typedef unsigned short u16;
typedef __attribute__((ext_vector_type(8))) short bf16x8;
typedef __attribute__((ext_vector_type(4))) float f32x4;

constexpr int NN = 100000;
constexpr int NE = 1600000;
constexpr int PAD = 100352;            // 196 * 512
constexpr int NBUCK = 196;             // buckets of 512 rows
constexpr int BCAP = 10240;            // per-bucket capacity (mean 8163)
constexpr int EPB = 4096;              // edges per part1 block
constexpr int P1B = (NE + EPB - 1) / EPB;   // 391 part1 blocks
constexpr int G0B = (NN + 63) / 64;         // 1563 gemm0 blocks

__device__ __forceinline__ u16 f2bf(float f) {   // RNE round to bf16
    u32 x = __float_as_uint(f);
    x += 0x7fffu + ((x >> 16) & 1u);
    return (u16)(x >> 16);
}

// ---------------------------------------------------------------------------
// Weight fp32 -> bf16 in B-fragment order; block 0 also zeroes bcur.
// ---------------------------------------------------------------------------
__device__ __forceinline__ void wfrag_one(const float* __restrict__ W,
                                          u16* __restrict__ Wf, int total, int i)
{
    if (i < total) {
        const int j    = i & 7;
        const int lane = (i >> 3) & 63;
        const int kc   = (i >> 9) & 3;
        const int ct   = i >> 11;
        const int src  = (ct * 16 + (lane & 15)) * 128 + kc * 32 + (lane >> 4) * 8 + j;
        Wf[i] = f2bf(W[src]);
    }
}

__global__ __launch_bounds__(256)
void wcvt_kernel(const float* __restrict__ W0, const float* __restrict__ W1,
                 const float* __restrict__ W2, u16* __restrict__ wf0,
                 u16* __restrict__ wf1, u16* __restrict__ wf2,
                 int* __restrict__ bcur)
{
    const int i = blockIdx.x * 256 + threadIdx.x;
    if (blockIdx.x == 0) bcur[threadIdx.x] = 0;
    wfrag_one(W0, wf0, 128 * 128, i);
    wfrag_one(W1, wf1, 128 * 128, i);
    wfrag_one(W2, wf2, 64 * 128, i);
}

// ---------------------------------------------------------------------------
// K1: blocks [0, P1B) = part1 (bucket partition, streaming two-pass);
//     blocks [P1B, P1B+G0B) = gemm0 (t0 = x @ W0^T, bf16 MFMA).
// Shared LDS buffer sized for the gemm branch (17408 B).
// ---------------------------------------------------------------------------
__global__ __launch_bounds__(256)
void k1_kernel(const float* __restrict__ x, const u16* __restrict__ Wf,
               u16* __restrict__ Cb,
               const int* __restrict__ erow, const int* __restrict__ ecol,
               const float* __restrict__ eval, int* __restrict__ bcur,
               int2* __restrict__ part)
{
    __shared__ u16 smem[64 * 136];     // gemm: sA/sC; part1: shist/sbase
    const int tid = threadIdx.x;

    if ((int)blockIdx.x < P1B) {
        // ---------------- part1 branch ----------------
        int* shist = (int*)smem;
        int* sbase = shist + NBUCK;
        for (int i = tid; i < NBUCK; i += 256) shist[i] = 0;
        __syncthreads();

        const int base = blockIdx.x * EPB;
        #pragma unroll
        for (int j = 0; j < EPB / 256; ++j) {
            const int e = base + j * 256 + tid;
            if (e < NE) atomicAdd(&shist[erow[e] >> 9], 1);
        }
        __syncthreads();
        for (int i = tid; i < NBUCK; i += 256) {
            const int c = shist[i];
            sbase[i] = c ? atomicAdd(&bcur[i], c) : 0;
            shist[i] = 0;
        }
        __syncthreads();
        #pragma unroll
        for (int j = 0; j < EPB / 256; ++j) {
            const int e = base + j * 256 + tid;
            if (e < NE) {
                const int r = erow[e];
                const int b = r >> 9;
                const int rk = atomicAdd(&shist[b], 1);
                part[b * BCAP + sbase[b] + rk] =
                    make_int2(((r & 511) << 17) | ecol[e], __float_as_int(eval[e]));
            }
        }
        return;
    }

    // ---------------- gemm0 branch ----------------
    constexpr int RS   = 136;
    constexpr int PADW = 136;          // DO=128 + 8
    u16* sA = smem;
    u16* sC = smem;
    const int w    = tid >> 6;
    const int lane = tid & 63;
    const int m    = lane & 15;
    const int q    = lane >> 4;
    const int rowBase = ((int)blockIdx.x - P1B) * 64;

    #pragma unroll
    for (int i = 0; i < 8; ++i) {
        const int g = (i * 256 + tid) * 4;
        const int r = g >> 7, c = g & 127;
        float4 v = make_float4(0.f, 0.f, 0.f, 0.f);
        if (rowBase + r < NN) v = *(const float4*)(x + (size_t)(rowBase + r) * 128 + c);
        u16* d = &sA[r * RS + c];
        d[0] = f2bf(v.x); d[1] = f2bf(v.y); d[2] = f2bf(v.z); d[3] = f2bf(v.w);
    }
    __syncthreads();

    bf16x8 afrag[4];
    #pragma unroll
    for (int kc = 0; kc < 4; ++kc)
        afrag[kc] = *(const bf16x8*)&sA[(w * 16 + m) * RS + kc * 32 + q * 8];
    __syncthreads();

    #pragma unroll
    for (int ct = 0; ct < 8; ++ct) {
        f32x4 acc = {0.f, 0.f, 0.f, 0.f};
        #pragma unroll
        for (int kc = 0; kc < 4; ++kc) {
            const bf16x8 b = *(const bf16x8*)(Wf + (((ct * 4 + kc) * 64) + lane) * 8);
            acc = __builtin_amdgcn_mfma_f32_16x16x32_bf16(afrag[kc], b, acc, 0, 0, 0);
        }
        #pragma unroll
        for (int r = 0; r < 4; ++r)
            sC[(w * 16 + q * 4 + r) * PADW + ct * 16 + m] = f2bf(acc[r]);
    }
    __syncthreads();

    const int g    = lane >> 2;
    const int cb   = (lane & 3) * 32;
    const int grow = rowBase + w * 16 + g;
    if (grow < NN) {
        #pragma unroll
        for (int i = 0; i < 4; ++i) {
            const int4 v = *(const int4*)&sC[(w * 16 + g) * PADW + cb + i * 8];
            *(int4*)(Cb + (size_t)grow * 128 + cb + i * 8) = v;
        }
    }
}

// ---------------------------------------------------------------------------
// part2: local bucket-prefix scan + per-bucket row histogram + 512-wide
// LDS scan -> offs; LDS-cursor scatter into contiguous CSR slice.
// ---------------------------------------------------------------------------
__global__ __launch_bounds__(256)
void part2_kernel(const int* __restrict__ bcur, const int2* __restrict__ part,
                  int* __restrict__ offs, int2* __restrict__ pce)
{
    __shared__ int scnt[512];
    __shared__ int sdata[256];
    __shared__ int rowoff[512];
    const int b = blockIdx.x;
    const int tid = threadIdx.x;

    const int bv = (tid < NBUCK) ? bcur[tid] : 0;
    sdata[tid] = bv;
    __syncthreads();
    #pragma unroll
    for (int off = 1; off < 256; off <<= 1) {
        const int val = (tid >= off) ? sdata[tid - off] : 0;
        __syncthreads();
        sdata[tid] += val;
        __syncthreads();
    }
    const int gb = (b > 0) ? sdata[b - 1] : 0;
    const int cnt = bcur[b];
    __syncthreads();

    scnt[tid] = 0; scnt[tid + 256] = 0;
    __syncthreads();

    const int2* src = part + (size_t)b * BCAP;
    for (int i = tid; i < cnt; i += 256)
        atomicAdd(&scnt[((u32)src[i].x) >> 17], 1);
    __syncthreads();

    const int c0 = scnt[2 * tid];
    const int c1 = scnt[2 * tid + 1];
    const int tsum = c0 + c1;
    sdata[tid] = tsum;
    __syncthreads();
    #pragma unroll
    for (int off = 1; off < 256; off <<= 1) {
        const int val = (tid >= off) ? sdata[tid - off] : 0;
        __syncthreads();
        sdata[tid] += val;
        __syncthreads();
    }
    const int excl = sdata[tid] - tsum;
    rowoff[2 * tid]     = gb + excl;
    rowoff[2 * tid + 1] = gb + excl + c0;
    __syncthreads();

    offs[b * 512 + tid]       = rowoff[tid];
    offs[b * 512 + 256 + tid] = rowoff[tid + 256];
    __syncthreads();

    for (int i = tid; i < cnt; i += 256) {
        const int2 ev = src[i];
        const int rl = ((u32)ev.x) >> 17;
        const int pos = atomicAdd(&rowoff[rl], 1);
        pce[pos] = make_int2(ev.x & 0x1FFFF, ev.y);
    }
}

// ---------------------------------------------------------------------------
// Gather helpers (bf16 rows, fp32 accumulate).
// ---------------------------------------------------------------------------
template<int LPC>
__device__ __forceinline__ void load_row(const u16* p, u32* u) {
    if constexpr (LPC == 8) {
        const uint4 t = *(const uint4*)p;
        u[0] = t.x; u[1] = t.y; u[2] = t.z; u[3] = t.w;
    } else {
        const uint2 t = *(const uint2*)p;
        u[0] = t.x; u[1] = t.y;
    }
}

template<int LPC>
__device__ __forceinline__ void fma_row(float v, const u32* u, float* a) {
    #pragma unroll
    for (int j = 0; j < LPC / 2; ++j) {
        a[2*j]   = fmaf(v, __uint_as_float(u[j] << 16),         a[2*j]);
        a[2*j+1] = fmaf(v, __uint_as_float(u[j] & 0xffff0000u), a[2*j+1]);
    }
}

// ---------------------------------------------------------------------------
// Fused SpMM+GEMM: gather 16 rows of A*t -> relu(+residual) -> LDS A-tile
// -> mfma vs fragment-ordered Wf -> coalesced C store.
// MODE 1 also writes relu'd rows (h1) to Hout for the later residual.
// ---------------------------------------------------------------------------
template<int DO, int MODE>
__global__ __launch_bounds__(256)
void spmm_gemm(const int* __restrict__ offs, const int2* __restrict__ pce,
               const u16* __restrict__ Hb, const u16* __restrict__ Wf,
               const u16* __restrict__ Res, u16* __restrict__ Cb,
               u16* __restrict__ Hout)
{
    constexpr int RS   = 136;
    constexpr int PADW = DO + 8;
    __shared__ u16 smem[16 * 136];
    const int tid = threadIdx.x;
    const int ln  = tid & 15;
    const int rl  = tid >> 4;
    const int row = blockIdx.x * 16 + rl;

    const int s = offs[row];
    const int t = offs[row + 1];
    const u16* hbase = Hb + ln * 8;

    float a0[8], a1[8];
    #pragma unroll
    for (int j = 0; j < 8; ++j) { a0[j] = 0.f; a1[j] = 0.f; }

    int e = s;
    for (; e + 1 < t; e += 2) {
        const int2 e0 = pce[e];
        const int2 e1 = pce[e + 1];
        u32 u0[4], u1[4];
        load_row<8>(hbase + (size_t)e0.x * 128, u0);
        load_row<8>(hbase + (size_t)e1.x * 128, u1);
        fma_row<8>(__int_as_float(e0.y), u0, a0);
        fma_row<8>(__int_as_float(e1.y), u1, a1);
    }
    if (e < t) {
        const int2 e0 = pce[e];
        u32 u0[4];
        load_row<8>(hbase + (size_t)e0.x * 128, u0);
        fma_row<8>(__int_as_float(e0.y), u0, a0);
    }
    #pragma unroll
    for (int j = 0; j < 8; ++j) a0[j] = fmaxf(a0[j] + a1[j], 0.f);

    if constexpr (MODE == 2) {
        u32 r[4];
        load_row<8>(Res + (size_t)row * 128 + ln * 8, r);
        #pragma unroll
        for (int j = 0; j < 4; ++j) {
            a0[2*j]   += __uint_as_float(r[j] << 16);
            a0[2*j+1] += __uint_as_float(r[j] & 0xffff0000u);
        }
    }
    u32 o[4];
    #pragma unroll
    for (int j = 0; j < 4; ++j)
        o[j] = (u32)f2bf(a0[2*j]) | ((u32)f2bf(a0[2*j+1]) << 16);
    const uint4 packed = make_uint4(o[0], o[1], o[2], o[3]);
    *(uint4*)&smem[rl * RS + ln * 8] = packed;
    if constexpr (MODE == 1)
        *(uint4*)(Hout + (size_t)row * 128 + ln * 8) = packed;
    __syncthreads();

    constexpr int TPW = DO / 64;
    const int w    = tid >> 6;
    const int lane = tid & 63;
    const int m    = lane & 15;
    const int q    = lane >> 4;

    bf16x8 afrag[4];
    #pragma unroll
    for (int kc = 0; kc < 4; ++kc)
        afrag[kc] = *(const bf16x8*)&smem[m * RS + kc * 32 + q * 8];

    f32x4 acc[TPW];
    #pragma unroll
    for (int tw = 0; tw < TPW; ++tw) {
        const int ct = w * TPW + tw;
        acc[tw] = (f32x4){0.f, 0.f, 0.f, 0.f};
        #pragma unroll
        for (int kc = 0; kc < 4; ++kc) {
            const bf16x8 b = *(const bf16x8*)(Wf + (((ct * 4 + kc) * 64) + lane) * 8);
            acc[tw] = __builtin_amdgcn_mfma_f32_16x16x32_bf16(afrag[kc], b, acc[tw], 0, 0, 0);
        }
    }
    __syncthreads();

    #pragma unroll
    for (int tw = 0; tw < TPW; ++tw) {
        const int ct = w * TPW + tw;
        #pragma unroll
        for (int r = 0; r < 4; ++r)
            smem[(q * 4 + r) * PADW + ct * 16 + m] = f2bf(acc[tw][r]);
    }
    __syncthreads();

    if (DO == 128 || tid < 128) {
        const int g = tid * 8;
        const int r = g / DO;
        const int c = g % DO;
        const int4 v = *(const int4*)&smem[r * PADW + c];
        *(int4*)(Cb + ((size_t)blockIdx.x * 16 + r) * DO + c) = v;
    }
}

// ---------------------------------------------------------------------------
// Final CSR SpMM (layer 3): gather t2 (D=64), write fp32 out.
// ---------------------------------------------------------------------------
__global__ __launch_bounds__(256)
void spmm_out(const int* __restrict__ offs, const int2* __restrict__ pce,
              const u16* __restrict__ Hb, float* __restrict__ Y)
{
    const int ln  = threadIdx.x & 15;
    const int row = blockIdx.x * 16 + (threadIdx.x >> 4);
    if (row >= NN) return;
    const int s = offs[row];
    const int t = offs[row + 1];
    const u16* hbase = Hb + ln * 4;

    float a0[4], a1[4];
    #pragma unroll
    for (int j = 0; j < 4; ++j) { a0[j] = 0.f; a1[j] = 0.f; }

    int e = s;
    for (; e + 1 < t; e += 2) {
        const int2 e0 = pce[e];
        const int2 e1 = pce[e + 1];
        u32 u0[2], u1[2];
        load_row<4>(hbase + (size_t)e0.x * 64, u0);
        load_row<4>(hbase + (size_t)e1.x * 64, u1);
        fma_row<4>(__int_as_float(e0.y), u0, a0);
        fma_row<4>(__int_as_float(e1.y), u1, a1);
    }
    if (e < t) {
        const int2 e0 = pce[e];
        u32 u0[2];
        load_row<4>(hbase + (size_t)e0.x * 64, u0);
        fma_row<4>(__int_as_float(e0.y), u0, a0);
    }
    #pragma unroll
    for (int j = 0; j < 4; ++j) a0[j] += a1[j];
    *(float4*)(Y + (size_t)row * 64 + ln * 4) = make_float4(a0[0], a0[1], a0[2], a0[3]);
}

extern "C" void kernel_launch(void* const* d_in, const int* in_sizes, int n_in,
                              void* d_out, int out_size, void* d_ws, size_t ws_size,
                              hipStream_t stream) {
    const float* x    = (const float*)d_in[0];
    const int*   erow = (const int*)  d_in[1];
    const int*   ecol = (const int*)  d_in[2];
    const float* eval = (const float*)d_in[3];
    const float* W0   = (const float*)d_in[4];
    const float* W1   = (const float*)d_in[5];
    const float* W2   = (const float*)d_in[6];
    float* out = (float*)d_out;

    char* p = (char*)d_ws;
    const size_t BUFB = (size_t)NN * 128 * sizeof(u16);   // 25.6 MB
    u16* t0b  = (u16*)p;  p += BUFB;     // t0; reused for t2 (t0 dead by then)
    u16* t1b  = (u16*)p;  p += BUFB;
    u16* h1b  = (u16*)p;  p += BUFB;
    u16* wf0  = (u16*)p;  p += 128 * 128 * 2;
    u16* wf1  = (u16*)p;  p += 128 * 128 * 2;
    u16* wf2  = (u16*)p;  p += 64 * 128 * 2;
    int* bcur   = (int*)p; p += 256 * 4;
    int* offs   = (int*)p; p += ((size_t)PAD + 256) * 4;
    int2* part  = (int2*)p; p += (size_t)NBUCK * BCAP * 8;  // 16.06 MB
    int2* pce   = (int2*)p;                                 // 12.8 MB

    const dim3 blk(256);
    const int rowBlocks = NN / 16;     // 6250

    // wcvt (also zeroes bcur) -> K1 [part1 || gemm0] -> part2 -> F1 -> F2 -> out
    wcvt_kernel<<<64, blk, 0, stream>>>(W0, W1, W2, wf0, wf1, wf2, bcur);
    k1_kernel  <<<P1B + G0B, blk, 0, stream>>>(x, wf0, t0b, erow, ecol, eval, bcur, part);
    part2_kernel<<<NBUCK, blk, 0, stream>>>(bcur, part, offs, pce);
    spmm_gemm<128, 1><<<rowBlocks, blk, 0, stream>>>(offs, pce, t0b, wf1, nullptr, t1b, h1b);
    spmm_gemm<64, 2><<<rowBlocks, blk, 0, stream>>>(offs, pce, t1b, wf2, h1b, t0b, nullptr);
    spmm_out<<<rowBlocks, blk, 0, stream>>>(offs, pce, t0b, out);
}